// Round 1
// baseline (676.790 us; speedup 1.0000x reference)
//
#include <hip/hip_runtime.h>
#include <hip/hip_bf16.h>

// SAKE GNN: B=512 graphs, M=32 atoms, H=128, L=2 layers, F_IN=16.
// Block = one graph, 512 threads (8 waves). All GEMMs via mfma_f32_16x16x32_bf16.

#define NB 512
#define NM 32
#define NH 128

typedef __bf16 bf16x8 __attribute__((ext_vector_type(8)));
typedef unsigned short u16x8 __attribute__((ext_vector_type(8)));
typedef float f32x4 __attribute__((ext_vector_type(4)));

__device__ __forceinline__ unsigned short f2bf(float f) {
    unsigned int u = __float_as_uint(f);
    u = u + 0x7FFFu + ((u >> 16) & 1u);   // RNE
    return (unsigned short)(u >> 16);
}
__device__ __forceinline__ float bf2f(unsigned short s) {
    return __uint_as_float(((unsigned int)s) << 16);
}
__device__ __forceinline__ float silu_f(float v) {
    return v / (1.0f + __expf(-v));
}

// ---------------- weight transpose+bf16 prep into workspace ----------------
// ws layout (each matrix 128x128 = 16384 bf16, stored as WT[n][k] = W[k][n]):
//   l*6 + {0:WaT, 1:WbT, 2:We2T, 3:Wh1aT, 4:Wh1bT, 5:Wh2T}, 12:W_outT, 13:Wn1T
__global__ void prep_weights(const float* __restrict__ We1, const float* __restrict__ We2,
                             const float* __restrict__ Wh1, const float* __restrict__ Wh2,
                             const float* __restrict__ W_out, const float* __restrict__ Wn1,
                             unsigned short* __restrict__ ws) {
    int gid = blockIdx.x * blockDim.x + threadIdx.x;
    if (gid >= 14 * 16384) return;
    int mtx = gid >> 14;
    int el  = gid & 16383;
    int n = el >> 7, k = el & 127;
    int l    = (mtx < 12) ? (mtx / 6) : 0;
    int kind = (mtx < 12) ? (mtx % 6) : (6 + (mtx - 12));
    float v = 0.f;
    switch (kind) {
        case 0: v = We1[(l*257 +       k)*128 + n]; break;   // Wa = We1[l, :128]
        case 1: v = We1[(l*257 + 128 + k)*128 + n]; break;   // Wb = We1[l, 128:256]
        case 2: v = We2[(l*128 +       k)*128 + n]; break;
        case 3: v = Wh1[(l*256 +       k)*128 + n]; break;   // Wh1a
        case 4: v = Wh1[(l*256 + 128 + k)*128 + n]; break;   // Wh1b
        case 5: v = Wh2[(l*128 +       k)*128 + n]; break;
        case 6: v = W_out[k*128 + n]; break;
        case 7: v = Wn1[k*128 + n]; break;
    }
    ws[gid] = f2bf(v);
}

// ---------------- main fused kernel ----------------
__global__ __launch_bounds__(512) void sake_kernel(
    const float* __restrict__ h,   const float* __restrict__ x,
    const float* __restrict__ W_in,const float* __restrict__ b_in,
    const float* __restrict__ We1, const float* __restrict__ be1,
    const float* __restrict__ be2, const float* __restrict__ bh1,
    const float* __restrict__ bh2, const float* __restrict__ b_out,
    const float* __restrict__ bn1, const float* __restrict__ Wn2,
    const float* __restrict__ bn2, const unsigned short* __restrict__ wt,
    float* __restrict__ out)
{
    __shared__ __align__(16) float          s_d2[32*32];      // 4 KB
    __shared__ __align__(16) float          s_hg[32*129];     // 16.1 KB fp32 residual
    __shared__ __align__(16) unsigned short s_mimj[32*264];   // 16.5 KB bf16 (mi | mj+be1); reused as g fp32
    __shared__ __align__(16) unsigned short s_A1[32*136];     // 8.5 KB bf16 A-stage (hgb / ub)
    __shared__ __align__(16) unsigned short s_A2[32*136];     // 8.5 KB bf16 A-stage (agg / ho)
    __shared__ __align__(16) float          s_wd[128];
    __shared__ __align__(16) float          s_x[32*4];
    __shared__ __align__(16) float          s_ep[256];

    const int tid  = threadIdx.x;
    const int b    = blockIdx.x;
    const int w    = tid >> 6;        // wave 0..7
    const int lane = tid & 63;
    const int quad = lane >> 4;
    const int lm   = lane & 15;

    // ---- load x, d2, hg = h@W_in + b_in ----
    if (tid < 32) {
        s_x[tid*4+0] = x[(b*32+tid)*3+0];
        s_x[tid*4+1] = x[(b*32+tid)*3+1];
        s_x[tid*4+2] = x[(b*32+tid)*3+2];
    }
    __syncthreads();
    for (int p = tid; p < 1024; p += 512) {
        int i = p >> 5, j = p & 31;
        float dx = s_x[i*4+0]-s_x[j*4+0];
        float dy = s_x[i*4+1]-s_x[j*4+1];
        float dz = s_x[i*4+2]-s_x[j*4+2];
        s_d2[p] = dx*dx + dy*dy + dz*dz;
    }
    {
        int k = tid & 127, mg = tid >> 7;   // mg 0..3 -> 8 rows each
        float wcol[16];
        #pragma unroll
        for (int f = 0; f < 16; f++) wcol[f] = W_in[f*128 + k];
        float bi = b_in[k];
        for (int rr = 0; rr < 8; rr++) {
            int m = mg*8 + rr;
            const float4* h4 = (const float4*)(h + (size_t)(b*32 + m)*16);
            float acc = bi;
            #pragma unroll
            for (int q = 0; q < 4; q++) {
                float4 hv = h4[q];
                acc += hv.x*wcol[q*4+0] + hv.y*wcol[q*4+1]
                     + hv.z*wcol[q*4+2] + hv.w*wcol[q*4+3];
            }
            s_hg[m*129 + k] = acc;
        }
    }
    __syncthreads();

    for (int l = 0; l < 2; l++) {
        // ---- stage hg -> bf16 A1, load wd ----
        {
            int m = tid >> 4, c = (tid & 15) * 8;
            #pragma unroll
            for (int q = 0; q < 8; q++) s_A1[m*136 + c + q] = f2bf(s_hg[m*129 + c + q]);
        }
        if (tid < 128) s_wd[tid] = We1[(l*257 + 256)*128 + tid];
        __syncthreads();

        // ---- mi | mj GEMM: [32x128] @ [Wa | Wb] -> s_mimj (be1 folded into mj) ----
        {
            int mt = w & 1, ng = w >> 1;
            #pragma unroll
            for (int t4 = 0; t4 < 4; t4++) {
                int nt = ng + t4*4;                       // 0..15
                const unsigned short* bt = wt + (((size_t)l*6 + (nt < 8 ? 0 : 1)) << 14);
                int ncl = (nt & 7)*16 + lm;
                f32x4 acc = {0.f,0.f,0.f,0.f};
                #pragma unroll
                for (int kb = 0; kb < 4; kb++) {
                    bf16x8 a  = *(const bf16x8*)&s_A1[(mt*16+lm)*136 + kb*32 + quad*8];
                    bf16x8 bb = *(const bf16x8*)&bt[ncl*128 + kb*32 + quad*8];
                    acc = __builtin_amdgcn_mfma_f32_16x16x32_bf16(a, bb, acc, 0, 0, 0);
                }
                int c = nt*16 + lm;
                float bias = (nt >= 8) ? be1[l*128 + ncl] : 0.0f;
                #pragma unroll
                for (int r = 0; r < 4; r++)
                    s_mimj[(mt*16 + quad*4 + r)*264 + c] = f2bf(acc[r] + bias);
            }
        }
        __syncthreads();

        // ---- pair phase: silu1 -> (1024x128)@We2 -> silu2 -> mask -> agg ----
        {
            const unsigned short* we2t = wt + (((size_t)l*6 + 2) << 14);
            bf16x8 bfr[8][4];                              // hoisted We2^T B-frags (128 VGPR)
            #pragma unroll
            for (int nt = 0; nt < 8; nt++)
                #pragma unroll
                for (int kb = 0; kb < 4; kb++)
                    bfr[nt][kb] = *(const bf16x8*)&we2t[(nt*16+lm)*128 + kb*32 + quad*8];
            float be2v[8];
            #pragma unroll
            for (int nt = 0; nt < 8; nt++) be2v[nt] = be2[l*128 + nt*16 + lm];

            for (int ii = 0; ii < 4; ii++) {
                int i = ii*8 + w;                          // wave owns row i fully
                float vsum[8] = {0.f,0.f,0.f,0.f,0.f,0.f,0.f,0.f};
                #pragma unroll
                for (int g = 0; g < 2; g++) {
                    int j = g*16 + lm;
                    float d2v = s_d2[i*32 + j];
                    bf16x8 af[4];
                    #pragma unroll
                    for (int kb = 0; kb < 4; kb++) {
                        u16x8 miv = *(const u16x8*)&s_mimj[i*264 +       kb*32 + quad*8];
                        u16x8 mjv = *(const u16x8*)&s_mimj[j*264 + 128 + kb*32 + quad*8];
                        const float4* wd4 = (const float4*)&s_wd[kb*32 + quad*8];
                        float4 w0 = wd4[0], w1 = wd4[1];
                        float wdv[8] = {w0.x,w0.y,w0.z,w0.w,w1.x,w1.y,w1.z,w1.w};
                        u16x8 au;
                        #pragma unroll
                        for (int jj = 0; jj < 8; jj++) {
                            float a = bf2f(miv[jj]) + bf2f(mjv[jj]) + d2v*wdv[jj];
                            au[jj] = f2bf(silu_f(a));
                        }
                        af[kb] = __builtin_bit_cast(bf16x8, au);
                    }
                    float maskr[4];
                    #pragma unroll
                    for (int r = 0; r < 4; r++) {
                        int j2 = g*16 + quad*4 + r;        // D-frag row
                        float dd = s_d2[i*32 + j2];
                        maskr[r] = (dd < 1.0f && j2 != i) ? 1.0f : 0.0f;
                    }
                    #pragma unroll
                    for (int nt = 0; nt < 8; nt++) {
                        f32x4 acc = {0.f,0.f,0.f,0.f};
                        #pragma unroll
                        for (int kb = 0; kb < 4; kb++)
                            acc = __builtin_amdgcn_mfma_f32_16x16x32_bf16(af[kb], bfr[nt][kb], acc, 0, 0, 0);
                        #pragma unroll
                        for (int r = 0; r < 4; r++)
                            vsum[nt] += maskr[r] * silu_f(acc[r] + be2v[nt]);
                    }
                }
                #pragma unroll
                for (int nt = 0; nt < 8; nt++) {
                    float v = vsum[nt];
                    v += __shfl_xor(v, 16);
                    v += __shfl_xor(v, 32);
                    if (lane < 16) s_A2[i*136 + nt*16 + lane] = f2bf(v);  // agg (bf16 A-stage)
                }
            }
        }
        __syncthreads();

        // ---- u = silu(hg@Wh1a + agg@Wh1b + bh1) ----
        float uval[2][4];
        {
            const unsigned short* w1a = wt + (((size_t)l*6 + 3) << 14);
            const unsigned short* w1b = wt + (((size_t)l*6 + 4) << 14);
            int mt = w & 1, ng = w >> 1;
            #pragma unroll
            for (int t2 = 0; t2 < 2; t2++) {
                int nt = ng + t2*4, ncl = nt*16 + lm;
                f32x4 acc = {0.f,0.f,0.f,0.f};
                #pragma unroll
                for (int kb = 0; kb < 4; kb++) {
                    bf16x8 a  = *(const bf16x8*)&s_A1[(mt*16+lm)*136 + kb*32 + quad*8];
                    bf16x8 bb = *(const bf16x8*)&w1a[ncl*128 + kb*32 + quad*8];
                    acc = __builtin_amdgcn_mfma_f32_16x16x32_bf16(a, bb, acc, 0, 0, 0);
                }
                #pragma unroll
                for (int kb = 0; kb < 4; kb++) {
                    bf16x8 a  = *(const bf16x8*)&s_A2[(mt*16+lm)*136 + kb*32 + quad*8];
                    bf16x8 bb = *(const bf16x8*)&w1b[ncl*128 + kb*32 + quad*8];
                    acc = __builtin_amdgcn_mfma_f32_16x16x32_bf16(a, bb, acc, 0, 0, 0);
                }
                float bh = bh1[l*128 + ncl];
                #pragma unroll
                for (int r = 0; r < 4; r++) uval[t2][r] = silu_f(acc[r] + bh);
            }
        }
        __syncthreads();                                   // before overwriting A1 with u
        {
            int mt = w & 1, ng = w >> 1;
            #pragma unroll
            for (int t2 = 0; t2 < 2; t2++) {
                int nt = ng + t2*4;
                #pragma unroll
                for (int r = 0; r < 4; r++)
                    s_A1[(mt*16 + quad*4 + r)*136 + nt*16 + lm] = f2bf(uval[t2][r]);
            }
        }
        __syncthreads();

        // ---- hg += u@Wh2 + bh2 ----
        {
            const unsigned short* w2 = wt + (((size_t)l*6 + 5) << 14);
            int mt = w & 1, ng = w >> 1;
            #pragma unroll
            for (int t2 = 0; t2 < 2; t2++) {
                int nt = ng + t2*4, ncl = nt*16 + lm;
                f32x4 acc = {0.f,0.f,0.f,0.f};
                #pragma unroll
                for (int kb = 0; kb < 4; kb++) {
                    bf16x8 a  = *(const bf16x8*)&s_A1[(mt*16+lm)*136 + kb*32 + quad*8];
                    bf16x8 bb = *(const bf16x8*)&w2[ncl*128 + kb*32 + quad*8];
                    acc = __builtin_amdgcn_mfma_f32_16x16x32_bf16(a, bb, acc, 0, 0, 0);
                }
                float bh = bh2[l*128 + ncl];
                #pragma unroll
                for (int r = 0; r < 4; r++) {
                    int m = mt*16 + quad*4 + r;
                    s_hg[m*129 + ncl] += acc[r] + bh;
                }
            }
        }
        __syncthreads();
    }

    // ---- output head ----
    {
        int m = tid >> 4, c = (tid & 15) * 8;
        #pragma unroll
        for (int q = 0; q < 8; q++) s_A1[m*136 + c + q] = f2bf(s_hg[m*129 + c + q]);
    }
    __syncthreads();
    {   // ho = hg@W_out + b_out -> A2 (bf16)
        const unsigned short* wo = wt + ((size_t)12 << 14);
        int mt = w & 1, ng = w >> 1;
        #pragma unroll
        for (int t2 = 0; t2 < 2; t2++) {
            int nt = ng + t2*4, ncl = nt*16 + lm;
            f32x4 acc = {0.f,0.f,0.f,0.f};
            #pragma unroll
            for (int kb = 0; kb < 4; kb++) {
                bf16x8 a  = *(const bf16x8*)&s_A1[(mt*16+lm)*136 + kb*32 + quad*8];
                bf16x8 bb = *(const bf16x8*)&wo[ncl*128 + kb*32 + quad*8];
                acc = __builtin_amdgcn_mfma_f32_16x16x32_bf16(a, bb, acc, 0, 0, 0);
            }
            float bo = b_out[ncl];
            #pragma unroll
            for (int r = 0; r < 4; r++)
                s_A2[(mt*16 + quad*4 + r)*136 + ncl] = f2bf(acc[r] + bo);
        }
    }
    __syncthreads();
    float* s_g = (float*)s_mimj;                           // reuse (g is 32x129 fp32)
    {   // g = silu(ho@Wn1 + bn1) -> s_g fp32
        const unsigned short* wn1 = wt + ((size_t)13 << 14);
        int mt = w & 1, ng = w >> 1;
        #pragma unroll
        for (int t2 = 0; t2 < 2; t2++) {
            int nt = ng + t2*4, ncl = nt*16 + lm;
            f32x4 acc = {0.f,0.f,0.f,0.f};
            #pragma unroll
            for (int kb = 0; kb < 4; kb++) {
                bf16x8 a  = *(const bf16x8*)&s_A2[(mt*16+lm)*136 + kb*32 + quad*8];
                bf16x8 bb = *(const bf16x8*)&wn1[ncl*128 + kb*32 + quad*8];
                acc = __builtin_amdgcn_mfma_f32_16x16x32_bf16(a, bb, acc, 0, 0, 0);
            }
            float bn = bn1[ncl];
            #pragma unroll
            for (int r = 0; r < 4; r++)
                s_g[(mt*16 + quad*4 + r)*129 + ncl] = silu_f(acc[r] + bn);
        }
    }
    __syncthreads();
    // e = g @ Wn2 + bn2 ; out[b] = sum_m e[m]
    if (tid < 256) {
        int m = tid >> 3, s = tid & 7;
        float acc = 0.f;
        #pragma unroll
        for (int q = 0; q < 16; q++) {
            int hh = s*16 + q;
            acc += s_g[m*129 + hh] * Wn2[hh];
        }
        s_ep[tid] = acc;
    }
    __syncthreads();
    if (tid < 32) {
        float e = bn2[0];
        #pragma unroll
        for (int s = 0; s < 8; s++) e += s_ep[tid*8 + s];
        #pragma unroll
        for (int off = 16; off >= 1; off >>= 1) e += __shfl_down(e, off, 32);
        if (tid == 0) out[b] = e;
    }
}

extern "C" void kernel_launch(void* const* d_in, const int* in_sizes, int n_in,
                              void* d_out, int out_size, void* d_ws, size_t ws_size,
                              hipStream_t stream) {
    const float* h     = (const float*)d_in[0];
    const float* x     = (const float*)d_in[1];
    const float* W_in  = (const float*)d_in[3];
    const float* b_in  = (const float*)d_in[4];
    const float* We1   = (const float*)d_in[5];
    const float* be1   = (const float*)d_in[6];
    const float* We2   = (const float*)d_in[7];
    const float* be2   = (const float*)d_in[8];
    const float* Wh1   = (const float*)d_in[9];
    const float* bh1   = (const float*)d_in[10];
    const float* Wh2   = (const float*)d_in[11];
    const float* bh2   = (const float*)d_in[12];
    const float* W_out = (const float*)d_in[13];
    const float* b_out = (const float*)d_in[14];
    const float* Wn1   = (const float*)d_in[15];
    const float* bn1   = (const float*)d_in[16];
    const float* Wn2   = (const float*)d_in[17];
    const float* bn2   = (const float*)d_in[18];
    unsigned short* ws = (unsigned short*)d_ws;   // needs 14*16384*2 = 448 KB
    float* outp = (float*)d_out;

    prep_weights<<<896, 256, 0, stream>>>(We1, We2, Wh1, Wh2, W_out, Wn1, ws);
    sake_kernel<<<NB, 512, 0, stream>>>(h, x, W_in, b_in, We1, be1, be2, bh1, bh2,
                                        b_out, bn1, Wn2, bn2, ws, outp);
}